// Round 1
// 412.604 us; speedup vs baseline: 1.0443x; 1.0443x over previous
//
#include <hip/hip_runtime.h>

#define CN 16
#define HN 128
#define IMH 256
#define IMW 256
#define HW (IMH * IMW)

typedef __attribute__((ext_vector_type(8))) short short8;
typedef __attribute__((ext_vector_type(4))) float float4v;
typedef __attribute__((ext_vector_type(2))) unsigned int uint2v;
typedef __attribute__((ext_vector_type(4))) unsigned int uint4v;

__device__ __forceinline__ unsigned int f2bf(float f) {
    unsigned int u = __builtin_bit_cast(unsigned int, f);
    u += 0x7FFFu + ((u >> 16) & 1u);          // round-to-nearest-even
    return u >> 16;
}
// HW packed f32->bf16 (RNE, identical rounding to f2bf): 1 VALU op instead of ~10
__device__ __forceinline__ unsigned int pack2(float a, float b) {
    unsigned int r;
    asm("v_cvt_pk_bf16_f32 %0, %1, %2" : "=v"(r) : "v"(a), "v"(b));
    return r;
}

// ---------------- Weight prep: fragment-ordered bf16 weights ----------------
// a1f[((mi*2+ks)*64+lane)*8+j] = bf16(w1[16mi+(lane&15)][32ks+8(lane>>4)+j]),
//   with k==48 slot holding b1[hid] (bias folded via y[48]=1.0), k>48 -> 0.
// b2f[(ks*64+lane)*8+j]        = bf16(w2[lane&15][32ks+8(lane>>4)+j])
__global__ void nca_prep(const float* __restrict__ w1, const float* __restrict__ b1,
                         const float* __restrict__ w2,
                         unsigned short* __restrict__ a1f, unsigned short* __restrict__ b2f)
{
    int t = blockIdx.x * 256 + threadIdx.x;
    if (t < 8192) {
        int j = t & 7, lane = (t >> 3) & 63, ks = (t >> 9) & 1, mi = t >> 10;
        int hid = 16 * mi + (lane & 15);
        int k = 32 * ks + 8 * (lane >> 4) + j;
        float v = 0.f;
        if (k < 48) v = w1[hid * 48 + k];
        else if (k == 48) v = b1[hid];
        a1f[t] = (unsigned short)f2bf(v);
    }
    if (t < 2048) {
        int j = t & 7, lane = (t >> 3) & 63, ks = t >> 9;
        b2f[t] = (unsigned short)f2bf(w2[(lane & 15) * HN + 32 * ks + 8 * (lane >> 4) + j]);
    }
}

// ---------------- Kernel A: perception + MFMA MLP + update ----------------
// 128 pixels/block (4x32), 256 threads = 4 waves. Wave w owns pixels 32w..32w+31.
// LDS = 16384 (union) + 16384 (ybuf) + 8192 (xcT) = 40960 B exactly -> 4 blocks/CU.
__global__ __launch_bounds__(256, 4) void nca_mfma(
    const float* __restrict__ x, const float* __restrict__ upd,
    const unsigned short* __restrict__ a1f, const unsigned short* __restrict__ b2f,
    float* __restrict__ out, float* __restrict__ xn3, unsigned char* __restrict__ bm)
{
    __shared__ __align__(16) union {
        float sx[6][16][34];               // 13056 B (staging; dead after perception)
        unsigned short hb[4][16][128];     // 16384 B (per-wave h scratch, swizzled)
    } u;
    __shared__ __align__(16) unsigned short ybuf[128][64];   // 16384 B (swizzled, pitch 128B)
    __shared__ __align__(16) float xcT[16][128];             //  8192 B (x centers, XOR-swizzled)

    const int b   = blockIdx.z;
    const int i0  = blockIdx.y * 4;
    const int j0  = blockIdx.x * 32;
    const int tid = threadIdx.x;
    const int lane = tid & 63, w = tid >> 6;
    const int l15 = lane & 15, q = lane >> 4;
    const float* xb = x + (size_t)b * CN * HW;

    // ---- weight fragment loads (L1/L2-hot; consumed after sync2) ----
    short8 a1[8][2];
#pragma unroll
    for (int mi = 0; mi < 8; ++mi)
#pragma unroll
        for (int ks = 0; ks < 2; ++ks)
            a1[mi][ks] = *(const short8*)(a1f + ((mi * 2 + ks) * 64 + lane) * 8);
    short8 b2[4];
#pragma unroll
    for (int ks = 0; ks < 4; ++ks)
        b2[ks] = *(const short8*)(b2f + (ks * 64 + lane) * 8);

    // ---- stage x tile (+1 halo): layout sx[row 0..5][ch][col 0..33] ----
    const bool interior = (blockIdx.y > 0) & (blockIdx.y < 63) & (blockIdx.x > 0) & (blockIdx.x < 7);
    {
        const int col = tid & 31;
        if (interior) {
            const float* src = xb + (i0 - 1) * IMW + (j0 - 1);
#pragma unroll
            for (int rt = tid >> 5; rt < 96; rt += 8)
                u.sx[rt >> 4][rt & 15][col] = src[(rt & 15) * HW + (rt >> 4) * IMW + col];
            if (tid < 192) {
                int rt = tid >> 1, col2 = 32 + (tid & 1);
                u.sx[rt >> 4][rt & 15][col2] = src[(rt & 15) * HW + (rt >> 4) * IMW + col2];
            }
        } else {
#pragma unroll
            for (int rt = tid >> 5; rt < 96; rt += 8) {
                int rr = rt >> 4, c = rt & 15;
                int gi = i0 + rr - 1, gj = j0 + col - 1;
                float v = 0.f;
                if ((unsigned)gi < IMH && (unsigned)gj < IMW) v = xb[c * HW + gi * IMW + gj];
                u.sx[rr][c][col] = v;
            }
            if (tid < 192) {
                int rt = tid >> 1, col2 = 32 + (tid & 1);
                int rr = rt >> 4, c = rt & 15;
                int gi = i0 + rr - 1, gj = j0 + col2 - 1;
                float v = 0.f;
                if ((unsigned)gi < IMH && (unsigned)gj < IMW) v = xb[c * HW + gi * IMW + gj];
                u.sx[rr][c][col2] = v;
            }
        }
    }
    __syncthreads();

    // ---- perception: thread = (pixel, 8-channel half) ----
    const int pix = tid & 127;
    const int ty  = pix >> 5, tx = pix & 31;
    const int cb  = (tid >> 7) << 3;       // 0 or 8 (wave-uniform)
    float v[24];
#pragma unroll
    for (int c8 = 0; c8 < 8; ++c8) {
        const int c = cb + c8;
        float a00 = u.sx[ty][c][tx],     a01 = u.sx[ty][c][tx + 1],     a02 = u.sx[ty][c][tx + 2];
        float a10 = u.sx[ty + 1][c][tx], a11 = u.sx[ty + 1][c][tx + 1], a12 = u.sx[ty + 1][c][tx + 2];
        float a20 = u.sx[ty + 2][c][tx], a21 = u.sx[ty + 2][c][tx + 1], a22 = u.sx[ty + 2][c][tx + 2];
        v[3 * c8]     = a11;
        v[3 * c8 + 1] = ((a02 - a00) + 2.f * (a12 - a10) + (a22 - a20)) * 0.125f;
        v[3 * c8 + 2] = ((a20 - a00) + 2.f * (a21 - a01) + (a22 - a02)) * 0.125f;
        xcT[c][pix ^ ((c & 7) << 2)] = a11;     // XOR-swizzled (bits 2..4)
        if (cb == 0 && c8 == 3) {
            // begin-alive: maxpool3 of x ch3 (zero-pad == -inf pad since x >= 0)
            float m0 = fmaxf(fmaxf(fmaxf(a00, a01), fmaxf(a02, a10)),
                             fmaxf(fmaxf(a11, a12), fmaxf(fmaxf(a20, a21), a22)));
            bm[(size_t)b * HW + (i0 + ty) * IMW + (j0 + tx)] = (m0 > 0.1f) ? 1 : 0;
        }
    }
    {
        // pack 24 bf16 -> 3 swizzled 16B groups; cb==8 also writes pad groups 6,7
        unsigned int* yrow = (unsigned int*)&ybuf[pix][0];
        const int gbase = (cb >> 3) * 3;
        const int sw = pix & 7;
#pragma unroll
        for (int t = 0; t < 3; ++t) {
            uint4v g;
#pragma unroll
            for (int k = 0; k < 4; ++k) g[k] = pack2(v[8 * t + 2 * k], v[8 * t + 2 * k + 1]);
            *(uint4v*)&yrow[((gbase + t) ^ sw) << 2] = g;
        }
        if (cb == 8) {
            uint4v g6 = {0x3F80u, 0u, 0u, 0u};   // y[48] = 1.0 (bias column)
            uint4v g7 = {};
            *(uint4v*)&yrow[(6 ^ sw) << 2] = g6;
            *(uint4v*)&yrow[(7 ^ sw) << 2] = g7;
        }
    }
    __syncthreads();

    // ---- per wave: GEMM1-T (all 128 hid x 16 pix) -> h scratch -> GEMM2 -> epilogue ----
    const float* ub = upd + (size_t)b * HW;
    float* ob = out + (size_t)b * CN * HW;
    float* n3 = xn3 + (size_t)b * HW;
#pragma unroll
    for (int half = 0; half < 2; ++half) {
        const int nt  = 2 * w + half;
        const int row = 16 * nt + l15;
        const unsigned short* yr = &ybuf[row][0];
        const int rsw = row & 7;
        short8 y0 = *(const short8*)(yr + ((q ^ rsw) << 3));
        short8 y1 = *(const short8*)(yr + (((4 + q) ^ rsw) << 3));
        const int hsw = l15 & 7;
#pragma unroll
        for (int mi = 0; mi < 8; ++mi) {
            float4v acc = {};
            acc = __builtin_amdgcn_mfma_f32_16x16x32_bf16(a1[mi][0], y0, acc, 0, 0, 0);
            acc = __builtin_amdgcn_mfma_f32_16x16x32_bf16(a1[mi][1], y1, acc, 0, 0, 0);
            uint2v hp;
            hp[0] = pack2(fmaxf(acc[0], 0.f), fmaxf(acc[1], 0.f));
            hp[1] = pack2(fmaxf(acc[2], 0.f), fmaxf(acc[3], 0.f));
            // logical col 16mi+4q -> group 2mi+(q>>1), offset 4(q&1); XOR-swizzled
            *(uint2v*)&u.hb[w][l15][(((2 * mi + (q >> 1)) ^ hsw) << 3) + ((q & 1) << 2)] = hp;
        }
        float4v acc2 = {};
#pragma unroll
        for (int ks = 0; ks < 4; ++ks) {
            short8 hf = *(const short8*)&u.hb[w][l15][((4 * ks + q) ^ hsw) << 3];
            acc2 = __builtin_amdgcn_mfma_f32_16x16x32_bf16(hf, b2[ks], acc2, 0, 0, 0);
        }
        // epilogue: pixel p2 = 16nt+4q+r, channel = l15; 4 consecutive pixels -> dwordx4
        const int i  = i0 + (nt >> 1);
        const int jb = j0 + ((nt & 1) << 4) + (q << 2);
        float4v xc4 = *(const float4v*)&xcT[l15][(16 * nt + 4 * q) ^ ((l15 & 7) << 2)];
        float4v u4  = *(const float4v*)(ub + i * IMW + jb);
        float4v o;
#pragma unroll
        for (int r = 0; r < 4; ++r)
            o[r] = fmaf(acc2[r], (u4[r] <= 0.5f) ? 1.f : 0.f, xc4[r]);
        *(float4v*)(ob + l15 * HW + i * IMW + jb) = o;
        if (l15 == 3) *(float4v*)(n3 + i * IMW + jb) = o;
    }
}

// ---------------- Pass 2: alive masking ----------------
// alive = bm & (maxpool3(xn3) > 0.1); zero dead pixels in-place (own pixel only).
__global__ __launch_bounds__(256) void nca_pass2(
    const float* __restrict__ xn3, const unsigned char* __restrict__ bm,
    float* __restrict__ out)
{
    __shared__ float s[10][130];
    const int b  = blockIdx.z;
    const int i0 = blockIdx.y * 8;
    const int j0 = blockIdx.x * 128;
    const int tid = threadIdx.x;
    const float* n3 = xn3 + (size_t)b * HW;

    for (int idx = tid; idx < 10 * 130; idx += 256) {
        int r = idx / 130, c = idx - r * 130;
        int gi = i0 + r - 1, gj = j0 + c - 1;
        s[r][c] = ((unsigned)gi < IMH && (unsigned)gj < IMW) ? n3[gi * IMW + gj] : -1e30f;
    }
    __syncthreads();

    const int c = tid & 127, rh = (tid >> 7) * 4;
    const unsigned char* bmp = bm + (size_t)b * HW + (i0 + rh) * IMW + (j0 + c);
    float* ob = out + (size_t)b * CN * HW;
#pragma unroll
    for (int k = 0; k < 4; ++k) {
        const int r = rh + k;
        float m = fmaxf(fmaxf(fmaxf(s[r][c], s[r][c + 1]), fmaxf(s[r][c + 2], s[r + 1][c])),
                        fmaxf(fmaxf(s[r + 1][c + 1], s[r + 1][c + 2]),
                              fmaxf(fmaxf(s[r + 2][c], s[r + 2][c + 1]), s[r + 2][c + 2])));
        if (!((m > 0.1f) && bmp[k * IMW])) {
            const int i = i0 + r, j = j0 + c;
#pragma unroll
            for (int ch = 0; ch < CN; ++ch)
                ob[ch * HW + i * IMW + j] = 0.f;
        }
    }
}

extern "C" void kernel_launch(void* const* d_in, const int* in_sizes, int n_in,
                              void* d_out, int out_size, void* d_ws, size_t ws_size,
                              hipStream_t stream) {
    const float* x   = (const float*)d_in[0];
    const float* upd = (const float*)d_in[1];
    const float* w1  = (const float*)d_in[2];
    const float* b1  = (const float*)d_in[3];
    const float* w2  = (const float*)d_in[4];
    float* out = (float*)d_out;

    char* ws = (char*)d_ws;
    float* xn3          = (float*)ws;                            // 8 MiB
    unsigned char* bmp  = (unsigned char*)(ws + (8u << 20));     // 2 MiB
    unsigned short* a1f = (unsigned short*)(ws + (10u << 20));   // 16 KiB
    unsigned short* b2f = a1f + 8192;                            // 4 KiB

    nca_prep<<<32, 256, 0, stream>>>(w1, b1, w2, a1f, b2f);
    nca_mfma<<<dim3(8, 64, 32), 256, 0, stream>>>(x, upd, a1f, b2f, out, xn3, bmp);
    nca_pass2<<<dim3(2, 32, 32), 256, 0, stream>>>(xn3, bmp, out);
}